// Round 3
// baseline (487.820 us; speedup 1.0000x reference)
//
#include <hip/hip_runtime.h>
#include <cstdint>
#include <cstddef>

// ---------------------------------------------------------------------------
// GCN: out = relu(BN2(A' relu(BN1(A' BN0(X) W1)) W2)) Wf + bf
// A' = D^-1/2 (A+I) D^-1/2 via per-call CSR (sorted by dst).
// Conv biases b1,b2 cancel inside the following BatchNorm and are skipped.
// BN affine (a,b per column) is fused into GEMM X-staging.
// ---------------------------------------------------------------------------

#define CS_BLOCKS 1024

// ---- column stats + fused BN-param finalize (last block) ------------------
// st[0..127]=sum, st[128..255]=sumsq. done = per-layer counter (zeroed).
// Vectorized: each thread owns one float4 col-group x one of 8 row slots.
__global__ __launch_bounds__(256) void k_colstats(const float* __restrict__ X,
                                                  int n, float* __restrict__ st,
                                                  int* __restrict__ done,
                                                  const float* __restrict__ g,
                                                  const float* __restrict__ be,
                                                  float invn,
                                                  float* __restrict__ a,
                                                  float* __restrict__ b) {
    __shared__ float ls[8 * 128];
    __shared__ float lq[8 * 128];
    const int c4    = threadIdx.x & 31;   // float4 column group
    const int rslot = threadIdx.x >> 5;   // 0..7
    float4 s4  = make_float4(0.f, 0.f, 0.f, 0.f);
    float4 q4  = make_float4(0.f, 0.f, 0.f, 0.f);
    const float4* X4 = (const float4*)X;
    for (int r = blockIdx.x * 8 + rslot; r < n; r += CS_BLOCKS * 8) {
        float4 v = X4[(size_t)r * 32 + c4];
        s4.x += v.x; s4.y += v.y; s4.z += v.z; s4.w += v.w;
        q4.x = fmaf(v.x, v.x, q4.x); q4.y = fmaf(v.y, v.y, q4.y);
        q4.z = fmaf(v.z, v.z, q4.z); q4.w = fmaf(v.w, v.w, q4.w);
    }
    *(float4*)&ls[rslot * 128 + c4 * 4] = s4;
    *(float4*)&lq[rslot * 128 + c4 * 4] = q4;
    __syncthreads();
    if (threadIdx.x < 128) {
        int c = threadIdx.x;
        float t = 0.f;
        #pragma unroll
        for (int k = 0; k < 8; ++k) t += ls[k * 128 + c];
        atomicAdd(&st[c], t);
    } else {
        int c = threadIdx.x - 128;
        float t = 0.f;
        #pragma unroll
        for (int k = 0; k < 8; ++k) t += lq[k * 128 + c];
        atomicAdd(&st[128 + c], t);
    }
    __threadfence();
    __shared__ int lastflag;
    if (threadIdx.x == 0)
        lastflag = (atomicAdd(done, 1) == CS_BLOCKS - 1) ? 1 : 0;
    __syncthreads();
    if (lastflag && threadIdx.x < 128) {
        int c = threadIdx.x;
        float su = atomicAdd(&st[c], 0.f);        // coherent read
        float sq = atomicAdd(&st[128 + c], 0.f);
        float mu   = su * invn;
        float var  = sq * invn - mu * mu;
        float av   = g[c] * rsqrtf(var + 1e-5f);
        a[c] = av;
        b[c] = be[c] - mu * av;
    }
}

// ---- CSR build ------------------------------------------------------------
__global__ __launch_bounds__(256) void k_count(const int* __restrict__ dst, int e,
                                               int* __restrict__ cnt) {
    int i = blockIdx.x * 256 + threadIdx.x;
    if (i < e) atomicAdd(&cnt[dst[i]], 1);
}

__global__ __launch_bounds__(1024) void k_scanA(const int* __restrict__ cnt, int n,
                                                int* __restrict__ rs, int* __restrict__ bsum) {
    __shared__ int tmp[1024];
    int t = threadIdx.x;
    int i = blockIdx.x * 1024 + t;
    int v = (i < n) ? cnt[i] : 0;
    tmp[t] = v;
    __syncthreads();
    for (int off = 1; off < 1024; off <<= 1) {
        int x = (t >= off) ? tmp[t - off] : 0;
        __syncthreads();
        tmp[t] += x;
        __syncthreads();
    }
    if (i < n) rs[i] = tmp[t] - v;                 // exclusive within chunk
    if (t == 1023) bsum[blockIdx.x] = tmp[t];      // chunk total
}

// scanC: add chunk base (serial sum of bsum, per-block), dinv, rs[n]=e
__global__ __launch_bounds__(256) void k_scanC(int* __restrict__ rs,
                                               const int* __restrict__ bsum,
                                               const int* __restrict__ cnt,
                                               float* __restrict__ dinv,
                                               int n, int e) {
    __shared__ int base;
    int chunk = (int)(blockIdx.x >> 2);   // 4 blocks of 256 per 1024-chunk
    if (threadIdx.x == 0) {
        int s = 0;
        for (int c = 0; c < chunk; ++c) s += bsum[c];
        base = s;
    }
    __syncthreads();
    int i = blockIdx.x * 256 + threadIdx.x;
    if (i < n) {
        rs[i] += base;
        dinv[i] = rsqrtf((float)(cnt[i] + 1));   // +1 self loop
    }
    if (blockIdx.x == 0 && threadIdx.x == 0) rs[n] = e;
}

// fill: one packed 8B scatter per edge: (src, norm)
__global__ __launch_bounds__(256) void k_fill(const int* __restrict__ src,
                                              const int* __restrict__ dst, int e,
                                              const int* __restrict__ rs,
                                              int* __restrict__ cursor,
                                              const float* __restrict__ dinv,
                                              int2* __restrict__ ep) {
    int i = blockIdx.x * 256 + threadIdx.x;
    if (i < e) {
        int d = dst[i], s = src[i];
        int p = rs[d] + atomicAdd(&cursor[d], 1);
        float nm = dinv[s] * dinv[d];
        ep[p] = make_int2(s, __float_as_int(nm));
    }
}

// ---- GEMM: H[n][128] = f(X) @ W,  f = affine(+relu) fused on X load -------
__global__ __launch_bounds__(256) void k_gemm128(const float* __restrict__ X,
                                                 const float* __restrict__ W,
                                                 const float* __restrict__ a,
                                                 const float* __restrict__ b,
                                                 int relu,
                                                 float* __restrict__ H, int n) {
    __shared__ float wl[64 * 64];     // 16 KB (one K-half of one col-block)
    __shared__ float xl[64 * 132];    // 33.8 KB (padded stride 132)
    const int tid = threadIdx.x;
    const int cb  = blockIdx.y;       // 0/1: which 64 output cols
    const int row0 = blockIdx.x * 64;

    for (int i = tid; i < 64 * 32; i += 256) {
        int r = i >> 5, c4 = i & 31;
        int gr = row0 + r;
        float4 v = make_float4(0.f, 0.f, 0.f, 0.f);
        if (gr < n) v = ((const float4*)(X + (size_t)gr * 128))[c4];
        float4 a4 = ((const float4*)a)[c4];
        float4 b4 = ((const float4*)b)[c4];
        v.x = fmaf(v.x, a4.x, b4.x);
        v.y = fmaf(v.y, a4.y, b4.y);
        v.z = fmaf(v.z, a4.z, b4.z);
        v.w = fmaf(v.w, a4.w, b4.w);
        if (relu) {
            v.x = fmaxf(v.x, 0.f); v.y = fmaxf(v.y, 0.f);
            v.z = fmaxf(v.z, 0.f); v.w = fmaxf(v.w, 0.f);
        }
        *(float4*)&xl[r * 132 + (c4 << 2)] = v;
    }

    const int cg = tid & 15;   // 16 col groups x 4 cols
    const int rg = tid >> 4;   // 16 row groups x 4 rows
    float acc[4][4] = {{0.f}};

    for (int h = 0; h < 2; ++h) {
        __syncthreads();
        {
            float4* wl4 = (float4*)wl;
            const float4* W4 = (const float4*)W;
            for (int i = tid; i < 64 * 16; i += 256) {
                int r = i >> 4, c4 = i & 15;
                wl4[i] = W4[(size_t)(h * 64 + r) * 32 + cb * 16 + c4];
            }
        }
        __syncthreads();
        for (int c = 0; c < 64; c += 4) {
            float4 xv[4];
            #pragma unroll
            for (int i = 0; i < 4; ++i)
                xv[i] = *(const float4*)&xl[(rg * 4 + i) * 132 + h * 64 + c];
            #pragma unroll
            for (int cc = 0; cc < 4; ++cc) {
                float4 wv = *(const float4*)&wl[(c + cc) * 64 + cg * 4];
                #pragma unroll
                for (int i = 0; i < 4; ++i) {
                    float xs = (&xv[i].x)[cc];
                    acc[i][0] = fmaf(xs, wv.x, acc[i][0]);
                    acc[i][1] = fmaf(xs, wv.y, acc[i][1]);
                    acc[i][2] = fmaf(xs, wv.z, acc[i][2]);
                    acc[i][3] = fmaf(xs, wv.w, acc[i][3]);
                }
            }
        }
    }

    const int colbase = cb * 64 + cg * 4;
    #pragma unroll
    for (int i = 0; i < 4; ++i) {
        int gr = row0 + rg * 4 + i;
        if (gr < n) {
            float4 o = make_float4(acc[i][0], acc[i][1], acc[i][2], acc[i][3]);
            *(float4*)&H[(size_t)gr * 128 + colbase] = o;
        }
    }
}

// ---- aggregation: one wave per node, edge loop unrolled x8 for MLP --------
__global__ __launch_bounds__(256) void k_aggregate(const float* __restrict__ H,
                                                   const int* __restrict__ rs,
                                                   const int2* __restrict__ ep,
                                                   const float* __restrict__ dinv,
                                                   float* __restrict__ AGG, int n) {
    int wid  = (blockIdx.x * 256 + threadIdx.x) >> 6;   // one wave per node
    int lane = threadIdx.x & 63;
    if (wid >= n) return;
    float sn = dinv[wid]; sn = sn * sn;
    float2 acc = ((const float2*)(H + (size_t)wid * 128))[lane];
    acc.x *= sn; acc.y *= sn;
    int i  = rs[wid];
    int i1 = rs[wid + 1];
    for (; i + 8 <= i1; i += 8) {
        int2 p[8];
        float2 v[8];
        #pragma unroll
        for (int k = 0; k < 8; ++k) p[k] = ep[i + k];
        #pragma unroll
        for (int k = 0; k < 8; ++k)
            v[k] = ((const float2*)(H + (size_t)p[k].x * 128))[lane];
        #pragma unroll
        for (int k = 0; k < 8; ++k) {
            float w = __int_as_float(p[k].y);
            acc.x = fmaf(w, v[k].x, acc.x);
            acc.y = fmaf(w, v[k].y, acc.y);
        }
    }
    if (i + 4 <= i1) {
        int2 p[4];
        float2 v[4];
        #pragma unroll
        for (int k = 0; k < 4; ++k) p[k] = ep[i + k];
        #pragma unroll
        for (int k = 0; k < 4; ++k)
            v[k] = ((const float2*)(H + (size_t)p[k].x * 128))[lane];
        #pragma unroll
        for (int k = 0; k < 4; ++k) {
            float w = __int_as_float(p[k].y);
            acc.x = fmaf(w, v[k].x, acc.x);
            acc.y = fmaf(w, v[k].y, acc.y);
        }
        i += 4;
    }
    for (; i < i1; ++i) {
        int2 p = ep[i];
        float2 v = ((const float2*)(H + (size_t)p.x * 128))[lane];
        float w = __int_as_float(p.y);
        acc.x = fmaf(w, v.x, acc.x);
        acc.y = fmaf(w, v.y, acc.y);
    }
    ((float2*)(AGG + (size_t)wid * 128))[lane] = acc;
}

// ---- final projection: OUT = relu(a*X+b) @ Wf + bf  (128 -> 40) -----------
__global__ __launch_bounds__(256) void k_gemm_out(const float* __restrict__ X,
                                                  const float* __restrict__ Wf,
                                                  const float* __restrict__ bfv,
                                                  const float* __restrict__ a,
                                                  const float* __restrict__ b,
                                                  float* __restrict__ OUT, int n) {
    __shared__ float xl[32 * 132];    // 16.9 KB
    __shared__ float wt[40 * 132];    // 21.1 KB, transposed Wf: wt[j][c]
    const int tid = threadIdx.x;

    for (int i = tid; i < 128 * 40; i += 256) {
        int c = i / 40;
        int j = i - c * 40;
        wt[j * 132 + c] = Wf[i];
    }
    const int row0 = blockIdx.x * 32;
    for (int i = tid; i < 32 * 32; i += 256) {
        int r = i >> 5, c4 = i & 31;
        int gr = row0 + r;
        float4 v = make_float4(0.f, 0.f, 0.f, 0.f);
        if (gr < n) v = ((const float4*)(X + (size_t)gr * 128))[c4];
        float4 a4 = ((const float4*)a)[c4];
        float4 b4 = ((const float4*)b)[c4];
        v.x = fmaxf(fmaf(v.x, a4.x, b4.x), 0.f);
        v.y = fmaxf(fmaf(v.y, a4.y, b4.y), 0.f);
        v.z = fmaxf(fmaf(v.z, a4.z, b4.z), 0.f);
        v.w = fmaxf(fmaf(v.w, a4.w, b4.w), 0.f);
        *(float4*)&xl[r * 132 + (c4 << 2)] = v;
    }
    __syncthreads();

    const int rg = tid >> 3;   // 32 rows
    const int cg = tid & 7;    // 8 groups x 5 cols
    const int j0 = cg * 5;
    float acc[5] = {0.f, 0.f, 0.f, 0.f, 0.f};
    for (int c = 0; c < 128; c += 4) {
        float4 xv = *(const float4*)&xl[rg * 132 + c];
        #pragma unroll
        for (int j = 0; j < 5; ++j) {
            float4 wv = *(const float4*)&wt[(j0 + j) * 132 + c];
            acc[j] = fmaf(xv.x, wv.x, acc[j]);
            acc[j] = fmaf(xv.y, wv.y, acc[j]);
            acc[j] = fmaf(xv.z, wv.z, acc[j]);
            acc[j] = fmaf(xv.w, wv.w, acc[j]);
        }
    }
    int gr = row0 + rg;
    if (gr < n) {
        #pragma unroll
        for (int j = 0; j < 5; ++j)
            OUT[(size_t)gr * 40 + j0 + j] = acc[j] + bfv[j0 + j];
    }
}

// ---------------------------------------------------------------------------
extern "C" void kernel_launch(void* const* d_in, const int* in_sizes, int n_in,
                              void* d_out, int out_size, void* d_ws, size_t ws_size,
                              hipStream_t stream) {
    const float* X0      = (const float*)d_in[0];
    const int*   edgesrc = (const int*)d_in[1];
    const int*   edgedst = (const int*)d_in[2];
    const float* bn0g = (const float*)d_in[3];
    const float* bn0b = (const float*)d_in[4];
    const float* W1   = (const float*)d_in[5];
    // d_in[6] = b1: cancels in BN1
    const float* bn1g = (const float*)d_in[7];
    const float* bn1b = (const float*)d_in[8];
    const float* W2   = (const float*)d_in[9];
    // d_in[10] = b2: cancels in BN2
    const float* bn2g = (const float*)d_in[11];
    const float* bn2b = (const float*)d_in[12];
    const float* Wf   = (const float*)d_in[13];
    const float* bfv  = (const float*)d_in[14];

    const int n = in_sizes[0] / 128;
    const int e = in_sizes[1];
    float* OUT = (float*)d_out;

    // workspace layout
    float* H     = (float*)d_ws;                 // n*128
    float* AGG   = H + (size_t)n * 128;          // n*128
    float* dinv  = AGG + (size_t)n * 128;        // n
    int2*  ep    = (int2*)(dinv + n);            // e (packed src,norm)
    int*   cnt   = (int*)(ep + e);               // n
    int*   rs    = cnt + n;                      // n+1
    int*   cursor= rs + n + 1;                   // n
    int*   bsum  = cursor + n;                   // 64
    float* stats = (float*)(bsum + 64);          // 3*256 floats
    int*   done  = (int*)(stats + 768);          // 3 counters
    float* a0 = (float*)(done + 4); float* b0 = a0 + 128;
    float* a1 = b0 + 128;           float* b1 = a1 + 128;
    float* a2 = b1 + 128;           float* b2 = a2 + 128;

    hipMemsetAsync(cnt,    0, (size_t)n * sizeof(int), stream);
    hipMemsetAsync(cursor, 0, (size_t)n * sizeof(int), stream);
    hipMemsetAsync(stats,  0, 768 * sizeof(float) + 4 * sizeof(int), stream);

    const float invn = 1.f / (float)n;
    const int nb = (n + 1023) / 1024;

    // CSR build
    k_count<<<(e + 255) / 256, 256, 0, stream>>>(edgedst, e, cnt);
    k_scanA<<<nb, 1024, 0, stream>>>(cnt, n, rs, bsum);
    k_scanC<<<(n + 255) / 256, 256, 0, stream>>>(rs, bsum, cnt, dinv, n, e);
    k_fill<<<(e + 255) / 256, 256, 0, stream>>>(edgesrc, edgedst, e, rs, cursor,
                                                dinv, ep);

    dim3 g1((n + 63) / 64, 2);
    int aggBlocks = (int)(((size_t)n * 64 + 255) / 256);

    // layer 1
    k_colstats<<<CS_BLOCKS, 256, 0, stream>>>(X0, n, stats, done, bn0g, bn0b,
                                              invn, a0, b0);
    k_gemm128<<<g1, 256, 0, stream>>>(X0, W1, a0, b0, 0, H, n);
    k_aggregate<<<aggBlocks, 256, 0, stream>>>(H, rs, ep, dinv, AGG, n);

    // layer 2
    k_colstats<<<CS_BLOCKS, 256, 0, stream>>>(AGG, n, stats + 256, done + 1,
                                              bn1g, bn1b, invn, a1, b1);
    k_gemm128<<<g1, 256, 0, stream>>>(AGG, W2, a1, b1, 1, H, n);
    k_aggregate<<<aggBlocks, 256, 0, stream>>>(H, rs, ep, dinv, AGG, n);

    // head
    k_colstats<<<CS_BLOCKS, 256, 0, stream>>>(AGG, n, stats + 512, done + 2,
                                              bn2g, bn2b, invn, a2, b2);
    k_gemm_out<<<(n + 31) / 32, 256, 0, stream>>>(AGG, Wf, bfv, a2, b2, OUT, n);
}

// Round 4
// 343.087 us; speedup vs baseline: 1.4219x; 1.4219x over previous
//
#include <hip/hip_runtime.h>
#include <cstdint>
#include <cstddef>

// ---------------------------------------------------------------------------
// GCN: out = relu(BN2(A' relu(BN1(A' BN0(X) W1)) W2)) Wf + bf
// A' = D^-1/2 (A+I) D^-1/2 via per-call CSR (sorted by dst).
// Conv biases b1,b2 cancel inside the following BatchNorm and are skipped.
// BN affine (a,b per column) is fused into GEMM X-staging.
// BN stats: 2-stage (per-block partials -> tiny reduce), NO atomics/fences —
// a single __threadfence() per block was measured to idle the chip (r3).
// ---------------------------------------------------------------------------

#define CS_BLOCKS 512

// ---- stage 1: per-block column partials (sum, sumsq) ----------------------
// part[block*256 + c]  : c<128 -> sum of col c ; c>=128 -> sumsq of col c-128
__global__ __launch_bounds__(256) void k_colstats(const float* __restrict__ X,
                                                  int n,
                                                  float* __restrict__ part) {
    __shared__ float ls[8 * 128];
    __shared__ float lq[8 * 128];
    const int c4    = threadIdx.x & 31;   // float4 column group
    const int rslot = threadIdx.x >> 5;   // 0..7
    float4 s4 = make_float4(0.f, 0.f, 0.f, 0.f);
    float4 q4 = make_float4(0.f, 0.f, 0.f, 0.f);
    const float4* X4 = (const float4*)X;
    for (int r = blockIdx.x * 8 + rslot; r < n; r += CS_BLOCKS * 8) {
        float4 v = X4[(size_t)r * 32 + c4];
        s4.x += v.x; s4.y += v.y; s4.z += v.z; s4.w += v.w;
        q4.x = fmaf(v.x, v.x, q4.x); q4.y = fmaf(v.y, v.y, q4.y);
        q4.z = fmaf(v.z, v.z, q4.z); q4.w = fmaf(v.w, v.w, q4.w);
    }
    *(float4*)&ls[rslot * 128 + c4 * 4] = s4;
    *(float4*)&lq[rslot * 128 + c4 * 4] = q4;
    __syncthreads();
    float t = 0.f;
    if (threadIdx.x < 128) {
        int c = threadIdx.x;
        #pragma unroll
        for (int k = 0; k < 8; ++k) t += ls[k * 128 + c];
    } else {
        int c = threadIdx.x - 128;
        #pragma unroll
        for (int k = 0; k < 8; ++k) t += lq[k * 128 + c];
    }
    part[blockIdx.x * 256 + threadIdx.x] = t;
}

// ---- stage 2: reduce partials, emit BN affine (a,b) -----------------------
__global__ __launch_bounds__(256) void k_bnfinal(const float* __restrict__ part,
                                                 const float* __restrict__ g,
                                                 const float* __restrict__ be,
                                                 float invn,
                                                 float* __restrict__ a,
                                                 float* __restrict__ b) {
    __shared__ float sh[256];
    const int c = threadIdx.x;
    float t = 0.f;
    for (int blk = 0; blk < CS_BLOCKS; blk += 4) {
        t += part[(blk + 0) * 256 + c];
        t += part[(blk + 1) * 256 + c];
        t += part[(blk + 2) * 256 + c];
        t += part[(blk + 3) * 256 + c];
    }
    sh[c] = t;
    __syncthreads();
    if (c < 128) {
        float mu   = sh[c] * invn;
        float var  = sh[128 + c] * invn - mu * mu;
        float av   = g[c] * rsqrtf(var + 1e-5f);
        a[c] = av;
        b[c] = be[c] - mu * av;
    }
}

// ---- CSR build ------------------------------------------------------------
__global__ __launch_bounds__(256) void k_count(const int* __restrict__ dst, int e,
                                               int* __restrict__ cnt) {
    int i = blockIdx.x * 256 + threadIdx.x;
    if (i < e) atomicAdd(&cnt[dst[i]], 1);
}

__global__ __launch_bounds__(1024) void k_scanA(const int* __restrict__ cnt, int n,
                                                int* __restrict__ rs, int* __restrict__ bsum) {
    __shared__ int tmp[1024];
    int t = threadIdx.x;
    int i = blockIdx.x * 1024 + t;
    int v = (i < n) ? cnt[i] : 0;
    tmp[t] = v;
    __syncthreads();
    for (int off = 1; off < 1024; off <<= 1) {
        int x = (t >= off) ? tmp[t - off] : 0;
        __syncthreads();
        tmp[t] += x;
        __syncthreads();
    }
    if (i < n) rs[i] = tmp[t] - v;                 // exclusive within chunk
    if (t == 1023) bsum[blockIdx.x] = tmp[t];      // chunk total
}

// scanC: add chunk base (serial sum of bsum, per-block), dinv, rs[n]=e
__global__ __launch_bounds__(256) void k_scanC(int* __restrict__ rs,
                                               const int* __restrict__ bsum,
                                               const int* __restrict__ cnt,
                                               float* __restrict__ dinv,
                                               int n, int e) {
    __shared__ int base;
    int chunk = (int)(blockIdx.x >> 2);   // 4 blocks of 256 per 1024-chunk
    if (threadIdx.x == 0) {
        int s = 0;
        for (int c = 0; c < chunk; ++c) s += bsum[c];
        base = s;
    }
    __syncthreads();
    int i = blockIdx.x * 256 + threadIdx.x;
    if (i < n) {
        rs[i] += base;
        dinv[i] = rsqrtf((float)(cnt[i] + 1));   // +1 self loop
    }
    if (blockIdx.x == 0 && threadIdx.x == 0) rs[n] = e;
}

// fill: one packed 8B scatter per edge: (src, norm)
__global__ __launch_bounds__(256) void k_fill(const int* __restrict__ src,
                                              const int* __restrict__ dst, int e,
                                              const int* __restrict__ rs,
                                              int* __restrict__ cursor,
                                              const float* __restrict__ dinv,
                                              int2* __restrict__ ep) {
    int i = blockIdx.x * 256 + threadIdx.x;
    if (i < e) {
        int d = dst[i], s = src[i];
        int p = rs[d] + atomicAdd(&cursor[d], 1);
        float nm = dinv[s] * dinv[d];
        ep[p] = make_int2(s, __float_as_int(nm));
    }
}

// ---- GEMM: H[n][128] = f(X) @ W,  f = affine(+relu) fused on X load -------
__global__ __launch_bounds__(256) void k_gemm128(const float* __restrict__ X,
                                                 const float* __restrict__ W,
                                                 const float* __restrict__ a,
                                                 const float* __restrict__ b,
                                                 int relu,
                                                 float* __restrict__ H, int n) {
    __shared__ float wl[64 * 64];     // 16 KB (one K-half of one col-block)
    __shared__ float xl[64 * 132];    // 33.8 KB (padded stride 132)
    const int tid = threadIdx.x;
    const int cb  = blockIdx.y;       // 0/1: which 64 output cols
    const int row0 = blockIdx.x * 64;

    for (int i = tid; i < 64 * 32; i += 256) {
        int r = i >> 5, c4 = i & 31;
        int gr = row0 + r;
        float4 v = make_float4(0.f, 0.f, 0.f, 0.f);
        if (gr < n) v = ((const float4*)(X + (size_t)gr * 128))[c4];
        float4 a4 = ((const float4*)a)[c4];
        float4 b4 = ((const float4*)b)[c4];
        v.x = fmaf(v.x, a4.x, b4.x);
        v.y = fmaf(v.y, a4.y, b4.y);
        v.z = fmaf(v.z, a4.z, b4.z);
        v.w = fmaf(v.w, a4.w, b4.w);
        if (relu) {
            v.x = fmaxf(v.x, 0.f); v.y = fmaxf(v.y, 0.f);
            v.z = fmaxf(v.z, 0.f); v.w = fmaxf(v.w, 0.f);
        }
        *(float4*)&xl[r * 132 + (c4 << 2)] = v;
    }

    const int cg = tid & 15;   // 16 col groups x 4 cols
    const int rg = tid >> 4;   // 16 row groups x 4 rows
    float acc[4][4] = {{0.f}};

    for (int h = 0; h < 2; ++h) {
        __syncthreads();
        {
            float4* wl4 = (float4*)wl;
            const float4* W4 = (const float4*)W;
            for (int i = tid; i < 64 * 16; i += 256) {
                int r = i >> 4, c4 = i & 15;
                wl4[i] = W4[(size_t)(h * 64 + r) * 32 + cb * 16 + c4];
            }
        }
        __syncthreads();
        for (int c = 0; c < 64; c += 4) {
            float4 xv[4];
            #pragma unroll
            for (int i = 0; i < 4; ++i)
                xv[i] = *(const float4*)&xl[(rg * 4 + i) * 132 + h * 64 + c];
            #pragma unroll
            for (int cc = 0; cc < 4; ++cc) {
                float4 wv = *(const float4*)&wl[(c + cc) * 64 + cg * 4];
                #pragma unroll
                for (int i = 0; i < 4; ++i) {
                    float xs = (&xv[i].x)[cc];
                    acc[i][0] = fmaf(xs, wv.x, acc[i][0]);
                    acc[i][1] = fmaf(xs, wv.y, acc[i][1]);
                    acc[i][2] = fmaf(xs, wv.z, acc[i][2]);
                    acc[i][3] = fmaf(xs, wv.w, acc[i][3]);
                }
            }
        }
    }

    const int colbase = cb * 64 + cg * 4;
    #pragma unroll
    for (int i = 0; i < 4; ++i) {
        int gr = row0 + rg * 4 + i;
        if (gr < n) {
            float4 o = make_float4(acc[i][0], acc[i][1], acc[i][2], acc[i][3]);
            *(float4*)&H[(size_t)gr * 128 + colbase] = o;
        }
    }
}

// ---- aggregation: one wave per node, edge loop unrolled x8 for MLP --------
__global__ __launch_bounds__(256) void k_aggregate(const float* __restrict__ H,
                                                   const int* __restrict__ rs,
                                                   const int2* __restrict__ ep,
                                                   const float* __restrict__ dinv,
                                                   float* __restrict__ AGG, int n) {
    int wid  = (blockIdx.x * 256 + threadIdx.x) >> 6;   // one wave per node
    int lane = threadIdx.x & 63;
    if (wid >= n) return;
    float sn = dinv[wid]; sn = sn * sn;
    float2 acc = ((const float2*)(H + (size_t)wid * 128))[lane];
    acc.x *= sn; acc.y *= sn;
    int i  = rs[wid];
    int i1 = rs[wid + 1];
    for (; i + 8 <= i1; i += 8) {
        int2 p[8];
        float2 v[8];
        #pragma unroll
        for (int k = 0; k < 8; ++k) p[k] = ep[i + k];
        #pragma unroll
        for (int k = 0; k < 8; ++k)
            v[k] = ((const float2*)(H + (size_t)p[k].x * 128))[lane];
        #pragma unroll
        for (int k = 0; k < 8; ++k) {
            float w = __int_as_float(p[k].y);
            acc.x = fmaf(w, v[k].x, acc.x);
            acc.y = fmaf(w, v[k].y, acc.y);
        }
    }
    if (i + 4 <= i1) {
        int2 p[4];
        float2 v[4];
        #pragma unroll
        for (int k = 0; k < 4; ++k) p[k] = ep[i + k];
        #pragma unroll
        for (int k = 0; k < 4; ++k)
            v[k] = ((const float2*)(H + (size_t)p[k].x * 128))[lane];
        #pragma unroll
        for (int k = 0; k < 4; ++k) {
            float w = __int_as_float(p[k].y);
            acc.x = fmaf(w, v[k].x, acc.x);
            acc.y = fmaf(w, v[k].y, acc.y);
        }
        i += 4;
    }
    for (; i < i1; ++i) {
        int2 p = ep[i];
        float2 v = ((const float2*)(H + (size_t)p.x * 128))[lane];
        float w = __int_as_float(p.y);
        acc.x = fmaf(w, v.x, acc.x);
        acc.y = fmaf(w, v.y, acc.y);
    }
    ((float2*)(AGG + (size_t)wid * 128))[lane] = acc;
}

// ---- final projection: OUT = relu(a*X+b) @ Wf + bf  (128 -> 40) -----------
__global__ __launch_bounds__(256) void k_gemm_out(const float* __restrict__ X,
                                                  const float* __restrict__ Wf,
                                                  const float* __restrict__ bfv,
                                                  const float* __restrict__ a,
                                                  const float* __restrict__ b,
                                                  float* __restrict__ OUT, int n) {
    __shared__ float xl[32 * 132];    // 16.9 KB
    __shared__ float wt[40 * 132];    // 21.1 KB, transposed Wf: wt[j][c]
    const int tid = threadIdx.x;

    for (int i = tid; i < 128 * 40; i += 256) {
        int c = i / 40;
        int j = i - c * 40;
        wt[j * 132 + c] = Wf[i];
    }
    const int row0 = blockIdx.x * 32;
    for (int i = tid; i < 32 * 32; i += 256) {
        int r = i >> 5, c4 = i & 31;
        int gr = row0 + r;
        float4 v = make_float4(0.f, 0.f, 0.f, 0.f);
        if (gr < n) v = ((const float4*)(X + (size_t)gr * 128))[c4];
        float4 a4 = ((const float4*)a)[c4];
        float4 b4 = ((const float4*)b)[c4];
        v.x = fmaxf(fmaf(v.x, a4.x, b4.x), 0.f);
        v.y = fmaxf(fmaf(v.y, a4.y, b4.y), 0.f);
        v.z = fmaxf(fmaf(v.z, a4.z, b4.z), 0.f);
        v.w = fmaxf(fmaf(v.w, a4.w, b4.w), 0.f);
        *(float4*)&xl[r * 132 + (c4 << 2)] = v;
    }
    __syncthreads();

    const int rg = tid >> 3;   // 32 rows
    const int cg = tid & 7;    // 8 groups x 5 cols
    const int j0 = cg * 5;
    float acc[5] = {0.f, 0.f, 0.f, 0.f, 0.f};
    for (int c = 0; c < 128; c += 4) {
        float4 xv = *(const float4*)&xl[rg * 132 + c];
        #pragma unroll
        for (int j = 0; j < 5; ++j) {
            float4 wv = *(const float4*)&wt[(j0 + j) * 132 + c];
            acc[j] = fmaf(xv.x, wv.x, acc[j]);
            acc[j] = fmaf(xv.y, wv.y, acc[j]);
            acc[j] = fmaf(xv.z, wv.z, acc[j]);
            acc[j] = fmaf(xv.w, wv.w, acc[j]);
        }
    }
    int gr = row0 + rg;
    if (gr < n) {
        #pragma unroll
        for (int j = 0; j < 5; ++j)
            OUT[(size_t)gr * 40 + j0 + j] = acc[j] + bfv[j0 + j];
    }
}

// ---------------------------------------------------------------------------
extern "C" void kernel_launch(void* const* d_in, const int* in_sizes, int n_in,
                              void* d_out, int out_size, void* d_ws, size_t ws_size,
                              hipStream_t stream) {
    const float* X0      = (const float*)d_in[0];
    const int*   edgesrc = (const int*)d_in[1];
    const int*   edgedst = (const int*)d_in[2];
    const float* bn0g = (const float*)d_in[3];
    const float* bn0b = (const float*)d_in[4];
    const float* W1   = (const float*)d_in[5];
    // d_in[6] = b1: cancels in BN1
    const float* bn1g = (const float*)d_in[7];
    const float* bn1b = (const float*)d_in[8];
    const float* W2   = (const float*)d_in[9];
    // d_in[10] = b2: cancels in BN2
    const float* bn2g = (const float*)d_in[11];
    const float* bn2b = (const float*)d_in[12];
    const float* Wf   = (const float*)d_in[13];
    const float* bfv  = (const float*)d_in[14];

    const int n = in_sizes[0] / 128;
    const int e = in_sizes[1];
    float* OUT = (float*)d_out;

    // workspace layout
    float* H     = (float*)d_ws;                 // n*128
    float* AGG   = H + (size_t)n * 128;          // n*128
    float* dinv  = AGG + (size_t)n * 128;        // n
    int2*  ep    = (int2*)(dinv + n);            // e (packed src,norm)
    int*   cnt   = (int*)(ep + e);               // n
    int*   rs    = cnt + n;                      // n+1
    int*   cursor= rs + n + 1;                   // n
    int*   bsum  = cursor + n;                   // 64
    float* part  = (float*)(bsum + 64);          // CS_BLOCKS*256
    float* a0 = part + CS_BLOCKS * 256; float* b0 = a0 + 128;
    float* a1 = b0 + 128;               float* b1 = a1 + 128;
    float* a2 = b1 + 128;               float* b2 = a2 + 128;

    hipMemsetAsync(cnt,    0, (size_t)n * sizeof(int), stream);
    hipMemsetAsync(cursor, 0, (size_t)n * sizeof(int), stream);

    const float invn = 1.f / (float)n;
    const int nb = (n + 1023) / 1024;

    // CSR build
    k_count<<<(e + 255) / 256, 256, 0, stream>>>(edgedst, e, cnt);
    k_scanA<<<nb, 1024, 0, stream>>>(cnt, n, rs, bsum);
    k_scanC<<<(n + 255) / 256, 256, 0, stream>>>(rs, bsum, cnt, dinv, n, e);
    k_fill<<<(e + 255) / 256, 256, 0, stream>>>(edgesrc, edgedst, e, rs, cursor,
                                                dinv, ep);

    dim3 g1((n + 63) / 64, 2);
    int aggBlocks = (int)(((size_t)n * 64 + 255) / 256);

    // layer 1
    k_colstats<<<CS_BLOCKS, 256, 0, stream>>>(X0, n, part);
    k_bnfinal<<<1, 256, 0, stream>>>(part, bn0g, bn0b, invn, a0, b0);
    k_gemm128<<<g1, 256, 0, stream>>>(X0, W1, a0, b0, 0, H, n);
    k_aggregate<<<aggBlocks, 256, 0, stream>>>(H, rs, ep, dinv, AGG, n);

    // layer 2
    k_colstats<<<CS_BLOCKS, 256, 0, stream>>>(AGG, n, part);
    k_bnfinal<<<1, 256, 0, stream>>>(part, bn1g, bn1b, invn, a1, b1);
    k_gemm128<<<g1, 256, 0, stream>>>(AGG, W2, a1, b1, 1, H, n);
    k_aggregate<<<aggBlocks, 256, 0, stream>>>(H, rs, ep, dinv, AGG, n);

    // head
    k_colstats<<<CS_BLOCKS, 256, 0, stream>>>(AGG, n, part);
    k_bnfinal<<<1, 256, 0, stream>>>(part, bn2g, bn2b, invn, a2, b2);
    k_gemm_out<<<(n + 31) / 32, 256, 0, stream>>>(AGG, Wf, bfv, a2, b2, OUT, n);
}

// Round 5
// 278.624 us; speedup vs baseline: 1.7508x; 1.2314x over previous
//
#include <hip/hip_runtime.h>
#include <cstdint>
#include <cstddef>

// ---------------------------------------------------------------------------
// GCN: out = relu(BN2(A' relu(BN1(A' BN0(X) W1)) W2)) Wf + bf
// A' = D^-1/2 (A+I) D^-1/2 via per-call CSR (sorted by dst).
// Conv biases b1,b2 cancel inside the following BatchNorm and are skipped.
// BN affine (a,b per column) is fused into GEMM X-staging.
// GEMMs 128x128 use bf16 MFMA (16x16x32); hidden features H stored bf16 to
// halve the random-gather traffic in aggregation. AGG kept fp32.
// BN stats: 2-stage partials (no atomics/fences — r3: threadfence idled chip).
// ---------------------------------------------------------------------------

#define CS_BLOCKS 512

typedef short s8v __attribute__((ext_vector_type(8)));
typedef float f4v __attribute__((ext_vector_type(4)));

__device__ inline ushort f2bf(float f) {            // RNE float->bf16
    uint u = __float_as_uint(f);
    return (ushort)((u + 0x7fffu + ((u >> 16) & 1u)) >> 16);
}
__device__ inline float2 bf2f2(uint u) {            // packed 2xbf16 -> 2xf32
    float2 r;
    r.x = __uint_as_float(u << 16);
    r.y = __uint_as_float(u & 0xffff0000u);
    return r;
}

// ---- stage 1: per-block column partials (sum, sumsq) ----------------------
__global__ __launch_bounds__(256) void k_colstats(const float* __restrict__ X,
                                                  int n,
                                                  float* __restrict__ part) {
    __shared__ float ls[8 * 128];
    __shared__ float lq[8 * 128];
    const int c4    = threadIdx.x & 31;
    const int rslot = threadIdx.x >> 5;
    float4 s4 = make_float4(0.f, 0.f, 0.f, 0.f);
    float4 q4 = make_float4(0.f, 0.f, 0.f, 0.f);
    const float4* X4 = (const float4*)X;
    for (int r = blockIdx.x * 8 + rslot; r < n; r += CS_BLOCKS * 8) {
        float4 v = X4[(size_t)r * 32 + c4];
        s4.x += v.x; s4.y += v.y; s4.z += v.z; s4.w += v.w;
        q4.x = fmaf(v.x, v.x, q4.x); q4.y = fmaf(v.y, v.y, q4.y);
        q4.z = fmaf(v.z, v.z, q4.z); q4.w = fmaf(v.w, v.w, q4.w);
    }
    *(float4*)&ls[rslot * 128 + c4 * 4] = s4;
    *(float4*)&lq[rslot * 128 + c4 * 4] = q4;
    __syncthreads();
    float t = 0.f;
    if (threadIdx.x < 128) {
        int c = threadIdx.x;
        #pragma unroll
        for (int k = 0; k < 8; ++k) t += ls[k * 128 + c];
    } else {
        int c = threadIdx.x - 128;
        #pragma unroll
        for (int k = 0; k < 8; ++k) t += lq[k * 128 + c];
    }
    part[blockIdx.x * 256 + threadIdx.x] = t;
}

// ---- stage 2: reduce partials, emit BN affine (a,b) -----------------------
__global__ __launch_bounds__(256) void k_bnfinal(const float* __restrict__ part,
                                                 const float* __restrict__ g,
                                                 const float* __restrict__ be,
                                                 float invn,
                                                 float* __restrict__ a,
                                                 float* __restrict__ b) {
    __shared__ float sh[256];
    const int c = threadIdx.x;
    float t = 0.f;
    for (int blk = 0; blk < CS_BLOCKS; blk += 4) {
        t += part[(blk + 0) * 256 + c];
        t += part[(blk + 1) * 256 + c];
        t += part[(blk + 2) * 256 + c];
        t += part[(blk + 3) * 256 + c];
    }
    sh[c] = t;
    __syncthreads();
    if (c < 128) {
        float mu   = sh[c] * invn;
        float var  = sh[128 + c] * invn - mu * mu;
        float av   = g[c] * rsqrtf(var + 1e-5f);
        a[c] = av;
        b[c] = be[c] - mu * av;
    }
}

// ---- CSR build ------------------------------------------------------------
__global__ __launch_bounds__(256) void k_count(const int* __restrict__ dst, int e,
                                               int* __restrict__ cnt) {
    int i = blockIdx.x * 256 + threadIdx.x;
    if (i < e) atomicAdd(&cnt[dst[i]], 1);
}

__global__ __launch_bounds__(1024) void k_scanA(const int* __restrict__ cnt, int n,
                                                int* __restrict__ rs, int* __restrict__ bsum) {
    __shared__ int tmp[1024];
    int t = threadIdx.x;
    int i = blockIdx.x * 1024 + t;
    int v = (i < n) ? cnt[i] : 0;
    tmp[t] = v;
    __syncthreads();
    for (int off = 1; off < 1024; off <<= 1) {
        int x = (t >= off) ? tmp[t - off] : 0;
        __syncthreads();
        tmp[t] += x;
        __syncthreads();
    }
    if (i < n) rs[i] = tmp[t] - v;
    if (t == 1023) bsum[blockIdx.x] = tmp[t];
}

__global__ __launch_bounds__(256) void k_scanC(int* __restrict__ rs,
                                               const int* __restrict__ bsum,
                                               const int* __restrict__ cnt,
                                               float* __restrict__ dinv,
                                               int n, int e) {
    __shared__ int base;
    int chunk = (int)(blockIdx.x >> 2);
    if (threadIdx.x == 0) {
        int s = 0;
        for (int c = 0; c < chunk; ++c) s += bsum[c];
        base = s;
    }
    __syncthreads();
    int i = blockIdx.x * 256 + threadIdx.x;
    if (i < n) {
        rs[i] += base;
        dinv[i] = rsqrtf((float)(cnt[i] + 1));
    }
    if (blockIdx.x == 0 && threadIdx.x == 0) rs[n] = e;
}

__global__ __launch_bounds__(256) void k_fill(const int* __restrict__ src,
                                              const int* __restrict__ dst, int e,
                                              const int* __restrict__ rs,
                                              int* __restrict__ cursor,
                                              const float* __restrict__ dinv,
                                              int2* __restrict__ ep) {
    int i = blockIdx.x * 256 + threadIdx.x;
    if (i < e) {
        int d = dst[i], s = src[i];
        int p = rs[d] + atomicAdd(&cursor[d], 1);
        float nm = dinv[s] * dinv[d];
        ep[p] = make_int2(s, __float_as_int(nm));
    }
}

// ---- W pre-swizzle to MFMA frag order -------------------------------------
// frag fi = ct*4+ks (ct: 16-col tile, ks: 32-k step): 64 lanes x 8 bf16,
// lane l holds W[k = 32*ks + 8*(l>>4) + j][c = 16*ct + (l&15)], j=0..7.
__global__ __launch_bounds__(256) void k_prep_w(const float* __restrict__ W,
                                                ushort* __restrict__ Wswz) {
    int t  = blockIdx.x * 256 + threadIdx.x;   // 0..2047
    int l  = t & 63;
    int fi = t >> 6;
    int ks = fi & 3, ct = fi >> 2;
    int c  = ct * 16 + (l & 15);
    int k0 = ks * 32 + ((l >> 4) << 3);
    ushort o[8];
    #pragma unroll
    for (int j = 0; j < 8; ++j)
        o[j] = f2bf(W[(size_t)(k0 + j) * 128 + c]);
    ushort4* dst = (ushort4*)(Wswz + (size_t)t * 8);
    dst[0] = make_ushort4(o[0], o[1], o[2], o[3]);
    dst[1] = make_ushort4(o[4], o[5], o[6], o[7]);
}

// ---- MFMA GEMM: H_bf16[n][128] = bf16( f(X) @ W ) -------------------------
// Block: 64 rows, 256 threads = 4 waves; wave w owns rows w*16..w*16+15.
// X staged to LDS as bf16 with fused affine(+relu), XOR-swizzled rows.
// W frags read from global (L1/L2-resident, 32 KB).
__global__ __launch_bounds__(256) void k_gemm_mfma(const float* __restrict__ X,
                                                   const ushort* __restrict__ Wswz,
                                                   const float* __restrict__ av,
                                                   const float* __restrict__ bv,
                                                   int relu,
                                                   ushort* __restrict__ H, int n) {
    __shared__ ushort xb[64 * 128];   // 16 KB, swizzled: byte ^= (row&7)<<4
    const int tid  = threadIdx.x;
    const int row0 = blockIdx.x * 64;

    for (int i = tid; i < 64 * 32; i += 256) {
        int r = i >> 5, c4 = i & 31;
        int gr = row0 + r;
        float4 v = make_float4(0.f, 0.f, 0.f, 0.f);
        if (gr < n) v = ((const float4*)X)[(size_t)gr * 32 + c4];
        float4 a4 = ((const float4*)av)[c4];
        float4 b4 = ((const float4*)bv)[c4];
        v.x = fmaf(v.x, a4.x, b4.x);
        v.y = fmaf(v.y, a4.y, b4.y);
        v.z = fmaf(v.z, a4.z, b4.z);
        v.w = fmaf(v.w, a4.w, b4.w);
        if (relu) {
            v.x = fmaxf(v.x, 0.f); v.y = fmaxf(v.y, 0.f);
            v.z = fmaxf(v.z, 0.f); v.w = fmaxf(v.w, 0.f);
        }
        ushort4 pk = make_ushort4(f2bf(v.x), f2bf(v.y), f2bf(v.z), f2bf(v.w));
        int off = (r * 256 + c4 * 8) ^ ((r & 7) << 4);
        *(ushort4*)((char*)xb + off) = pk;
    }
    __syncthreads();

    const int wv = tid >> 6;
    const int l  = tid & 63;
    const int arow = wv * 16 + (l & 15);

    s8v afr[4];
    #pragma unroll
    for (int ks = 0; ks < 4; ++ks) {
        int off = (arow * 256 + ks * 64 + ((l >> 4) << 4)) ^ ((arow & 7) << 4);
        afr[ks] = *(const s8v*)((const char*)xb + off);
    }

    const s8v* wf = (const s8v*)Wswz;     // frag fi at wf[fi*64 + l]
    f4v acc[8];
    #pragma unroll
    for (int ct = 0; ct < 8; ++ct) {
        f4v c = {0.f, 0.f, 0.f, 0.f};
        #pragma unroll
        for (int ks = 0; ks < 4; ++ks) {
            s8v bb = wf[(ct * 4 + ks) * 64 + l];
            c = __builtin_amdgcn_mfma_f32_16x16x32_bf16(afr[ks], bb, c, 0, 0, 0);
        }
        acc[ct] = c;
    }

    // D layout: col = l&15, row = 4*(l>>4) + reg   (m89-verified)
    const int rbase = row0 + wv * 16 + ((l >> 4) << 2);
    const int cidx  = l & 15;
    #pragma unroll
    for (int r = 0; r < 4; ++r) {
        int gr = rbase + r;
        if (gr < n) {
            #pragma unroll
            for (int ct = 0; ct < 8; ++ct)
                H[(size_t)gr * 128 + ct * 16 + cidx] = f2bf(acc[ct][r]);
        }
    }
}

// ---- aggregation: one wave per node, bf16 H gather, unroll x16 ------------
__global__ __launch_bounds__(256) void k_aggregate(const ushort* __restrict__ H,
                                                   const int* __restrict__ rs,
                                                   const int2* __restrict__ ep,
                                                   const float* __restrict__ dinv,
                                                   float* __restrict__ AGG, int n) {
    int wid  = (blockIdx.x * 256 + threadIdx.x) >> 6;
    int lane = threadIdx.x & 63;
    if (wid >= n) return;
    float sn = dinv[wid]; sn = sn * sn;
    float2 self = bf2f2(((const uint*)(H + (size_t)wid * 128))[lane]);
    float2 acc;
    acc.x = self.x * sn; acc.y = self.y * sn;
    int i  = rs[wid];
    int i1 = rs[wid + 1];
    for (; i + 16 <= i1; i += 16) {
        int2 p[16];
        uint v[16];
        #pragma unroll
        for (int k = 0; k < 16; ++k) p[k] = ep[i + k];
        #pragma unroll
        for (int k = 0; k < 16; ++k)
            v[k] = ((const uint*)(H + (size_t)p[k].x * 128))[lane];
        #pragma unroll
        for (int k = 0; k < 16; ++k) {
            float w = __int_as_float(p[k].y);
            float2 f = bf2f2(v[k]);
            acc.x = fmaf(w, f.x, acc.x);
            acc.y = fmaf(w, f.y, acc.y);
        }
    }
    for (; i + 4 <= i1; i += 4) {
        int2 p[4];
        uint v[4];
        #pragma unroll
        for (int k = 0; k < 4; ++k) p[k] = ep[i + k];
        #pragma unroll
        for (int k = 0; k < 4; ++k)
            v[k] = ((const uint*)(H + (size_t)p[k].x * 128))[lane];
        #pragma unroll
        for (int k = 0; k < 4; ++k) {
            float w = __int_as_float(p[k].y);
            float2 f = bf2f2(v[k]);
            acc.x = fmaf(w, f.x, acc.x);
            acc.y = fmaf(w, f.y, acc.y);
        }
    }
    for (; i < i1; ++i) {
        int2 p = ep[i];
        float w = __int_as_float(p.y);
        float2 f = bf2f2(((const uint*)(H + (size_t)p.x * 128))[lane]);
        acc.x = fmaf(w, f.x, acc.x);
        acc.y = fmaf(w, f.y, acc.y);
    }
    ((float2*)(AGG + (size_t)wid * 128))[lane] = acc;
}

// ---- final projection: OUT = relu(a*X+b) @ Wf + bf  (128 -> 40) -----------
__global__ __launch_bounds__(256) void k_gemm_out(const float* __restrict__ X,
                                                  const float* __restrict__ Wf,
                                                  const float* __restrict__ bfv,
                                                  const float* __restrict__ a,
                                                  const float* __restrict__ b,
                                                  float* __restrict__ OUT, int n) {
    __shared__ float xl[32 * 132];
    __shared__ float wt[40 * 132];
    const int tid = threadIdx.x;

    for (int i = tid; i < 128 * 40; i += 256) {
        int c = i / 40;
        int j = i - c * 40;
        wt[j * 132 + c] = Wf[i];
    }
    const int row0 = blockIdx.x * 32;
    for (int i = tid; i < 32 * 32; i += 256) {
        int r = i >> 5, c4 = i & 31;
        int gr = row0 + r;
        float4 v = make_float4(0.f, 0.f, 0.f, 0.f);
        if (gr < n) v = ((const float4*)X)[(size_t)gr * 32 + c4];
        float4 a4 = ((const float4*)a)[c4];
        float4 b4 = ((const float4*)b)[c4];
        v.x = fmaxf(fmaf(v.x, a4.x, b4.x), 0.f);
        v.y = fmaxf(fmaf(v.y, a4.y, b4.y), 0.f);
        v.z = fmaxf(fmaf(v.z, a4.z, b4.z), 0.f);
        v.w = fmaxf(fmaf(v.w, a4.w, b4.w), 0.f);
        *(float4*)&xl[r * 132 + (c4 << 2)] = v;
    }
    __syncthreads();

    const int rg = tid >> 3;
    const int cg = tid & 7;
    const int j0 = cg * 5;
    float acc[5] = {0.f, 0.f, 0.f, 0.f, 0.f};
    for (int c = 0; c < 128; c += 4) {
        float4 xv = *(const float4*)&xl[rg * 132 + c];
        #pragma unroll
        for (int j = 0; j < 5; ++j) {
            float4 wv = *(const float4*)&wt[(j0 + j) * 132 + c];
            acc[j] = fmaf(xv.x, wv.x, acc[j]);
            acc[j] = fmaf(xv.y, wv.y, acc[j]);
            acc[j] = fmaf(xv.z, wv.z, acc[j]);
            acc[j] = fmaf(xv.w, wv.w, acc[j]);
        }
    }
    int gr = row0 + rg;
    if (gr < n) {
        #pragma unroll
        for (int j = 0; j < 5; ++j)
            OUT[(size_t)gr * 40 + j0 + j] = acc[j] + bfv[j0 + j];
    }
}

// ---------------------------------------------------------------------------
extern "C" void kernel_launch(void* const* d_in, const int* in_sizes, int n_in,
                              void* d_out, int out_size, void* d_ws, size_t ws_size,
                              hipStream_t stream) {
    const float* X0      = (const float*)d_in[0];
    const int*   edgesrc = (const int*)d_in[1];
    const int*   edgedst = (const int*)d_in[2];
    const float* bn0g = (const float*)d_in[3];
    const float* bn0b = (const float*)d_in[4];
    const float* W1   = (const float*)d_in[5];
    const float* bn1g = (const float*)d_in[7];
    const float* bn1b = (const float*)d_in[8];
    const float* W2   = (const float*)d_in[9];
    const float* bn2g = (const float*)d_in[11];
    const float* bn2b = (const float*)d_in[12];
    const float* Wf   = (const float*)d_in[13];
    const float* bfv  = (const float*)d_in[14];

    const int n = in_sizes[0] / 128;
    const int e = in_sizes[1];
    float* OUT = (float*)d_out;

    // workspace layout (16B-aligned chunks)
    ushort* H    = (ushort*)d_ws;                     // n*128 bf16 (n*256 B)
    float*  AGG  = (float*)(H + (size_t)n * 128);     // n*128 f32
    float*  dinv = AGG + (size_t)n * 128;             // n
    int2*   ep   = (int2*)(dinv + n);                 // e
    ushort* Wswz = (ushort*)(ep + e);                 // 2 * 16384 bf16
    int*    cnt  = (int*)(Wswz + 2 * 16384);          // n
    int*    rs   = cnt + n;                           // n+1
    int*  cursor = rs + n + 1;                        // n
    int*    bsum = cursor + n;                        // 64
    float*  part = (float*)(bsum + 64);               // CS_BLOCKS*256
    float* a0 = part + CS_BLOCKS * 256; float* b0 = a0 + 128;
    float* a1 = b0 + 128;               float* b1 = a1 + 128;
    float* a2 = b1 + 128;               float* b2 = a2 + 128;

    hipMemsetAsync(cnt,    0, (size_t)n * sizeof(int), stream);
    hipMemsetAsync(cursor, 0, (size_t)n * sizeof(int), stream);

    const float invn = 1.f / (float)n;
    const int nb = (n + 1023) / 1024;

    // W swizzle (independent of everything else)
    k_prep_w<<<8, 256, 0, stream>>>(W1, Wswz);
    k_prep_w<<<8, 256, 0, stream>>>(W2, Wswz + 16384);

    // CSR build
    k_count<<<(e + 255) / 256, 256, 0, stream>>>(edgedst, e, cnt);
    k_scanA<<<nb, 1024, 0, stream>>>(cnt, n, rs, bsum);
    k_scanC<<<(n + 255) / 256, 256, 0, stream>>>(rs, bsum, cnt, dinv, n, e);
    k_fill<<<(e + 255) / 256, 256, 0, stream>>>(edgesrc, edgedst, e, rs, cursor,
                                                dinv, ep);

    const int gemmBlocks = (n + 63) / 64;
    int aggBlocks = (int)(((size_t)n * 64 + 255) / 256);

    // layer 1
    k_colstats<<<CS_BLOCKS, 256, 0, stream>>>(X0, n, part);
    k_bnfinal<<<1, 256, 0, stream>>>(part, bn0g, bn0b, invn, a0, b0);
    k_gemm_mfma<<<gemmBlocks, 256, 0, stream>>>(X0, Wswz, a0, b0, 0, H, n);
    k_aggregate<<<aggBlocks, 256, 0, stream>>>(H, rs, ep, dinv, AGG, n);

    // layer 2
    k_colstats<<<CS_BLOCKS, 256, 0, stream>>>(AGG, n, part);
    k_bnfinal<<<1, 256, 0, stream>>>(part, bn1g, bn1b, invn, a1, b1);
    k_gemm_mfma<<<gemmBlocks, 256, 0, stream>>>(AGG, Wswz + 16384, a1, b1, 1, H, n);
    k_aggregate<<<aggBlocks, 256, 0, stream>>>(H, rs, ep, dinv, AGG, n);

    // head
    k_colstats<<<CS_BLOCKS, 256, 0, stream>>>(AGG, n, part);
    k_bnfinal<<<1, 256, 0, stream>>>(part, bn2g, bn2b, invn, a2, b2);
    k_gemm_out<<<(n + 31) / 32, 256, 0, stream>>>(AGG, Wf, bfv, a2, b2, OUT, n);
}

// Round 6
// 246.690 us; speedup vs baseline: 1.9775x; 1.1294x over previous
//
#include <hip/hip_runtime.h>
#include <cstdint>
#include <cstddef>

// ---------------------------------------------------------------------------
// GCN: out = relu(BN2(A' relu(BN1(A' BN0(X) W1)) W2)) Wf + bf
// A' = D^-1/2 (A+I) D^-1/2 via per-call CSR (sorted by dst).
// Conv biases b1,b2 cancel inside the following BatchNorm and are skipped.
// BN affine (a,b per column) is fused into GEMM X-staging.
// GEMMs 128x128 use bf16 MFMA (16x16x32); hidden H stored bf16 (halves the
// random-gather traffic). AGG kept fp32.
// BN1/BN2 stats are FUSED into k_aggregate (per-lane sum/sumsq of the fp32
// acc before the bf16-free store) -> 2048 partial rows -> redA(64) -> bnfinal.
// No float atomics / no threadfence anywhere (r3: fence idled the chip).
// ---------------------------------------------------------------------------

#define CS_BLOCKS  512
#define AGG_BLOCKS 2048

typedef short s8v __attribute__((ext_vector_type(8)));
typedef float f4v __attribute__((ext_vector_type(4)));

__device__ inline ushort f2bf(float f) {            // RNE float->bf16
    uint u = __float_as_uint(f);
    return (ushort)((u + 0x7fffu + ((u >> 16) & 1u)) >> 16);
}
__device__ inline float2 bf2f2(uint u) {            // packed 2xbf16 -> 2xf32
    float2 r;
    r.x = __uint_as_float(u << 16);
    r.y = __uint_as_float(u & 0xffff0000u);
    return r;
}

// ---- per-block column partials for X0 (sum, sumsq) ------------------------
__global__ __launch_bounds__(256) void k_colstats(const float* __restrict__ X,
                                                  int n,
                                                  float* __restrict__ part) {
    __shared__ float ls[8 * 128];
    __shared__ float lq[8 * 128];
    const int c4    = threadIdx.x & 31;
    const int rslot = threadIdx.x >> 5;
    float4 s4 = make_float4(0.f, 0.f, 0.f, 0.f);
    float4 q4 = make_float4(0.f, 0.f, 0.f, 0.f);
    const float4* X4 = (const float4*)X;
    for (int r = blockIdx.x * 8 + rslot; r < n; r += CS_BLOCKS * 8) {
        float4 v = X4[(size_t)r * 32 + c4];
        s4.x += v.x; s4.y += v.y; s4.z += v.z; s4.w += v.w;
        q4.x = fmaf(v.x, v.x, q4.x); q4.y = fmaf(v.y, v.y, q4.y);
        q4.z = fmaf(v.z, v.z, q4.z); q4.w = fmaf(v.w, v.w, q4.w);
    }
    *(float4*)&ls[rslot * 128 + c4 * 4] = s4;
    *(float4*)&lq[rslot * 128 + c4 * 4] = q4;
    __syncthreads();
    float t = 0.f;
    if (threadIdx.x < 128) {
        int c = threadIdx.x;
        #pragma unroll
        for (int k = 0; k < 8; ++k) t += ls[k * 128 + c];
    } else {
        int c = threadIdx.x - 128;
        #pragma unroll
        for (int k = 0; k < 8; ++k) t += lq[k * 128 + c];
    }
    part[blockIdx.x * 256 + threadIdx.x] = t;
}

// ---- collapse AGG_BLOCKS partial rows -> 64 rows (coalesced) --------------
__global__ __launch_bounds__(256) void k_redA(const float* __restrict__ part,
                                              float* __restrict__ part2) {
    const int c = threadIdx.x;
    const int b = blockIdx.x;           // 64 blocks x 32 rows
    float t = 0.f;
    #pragma unroll 4
    for (int j = 0; j < AGG_BLOCKS / 64; ++j)
        t += part[(size_t)(b * (AGG_BLOCKS / 64) + j) * 256 + c];
    part2[b * 256 + c] = t;
}

// ---- reduce partial rows, emit BN affine (a,b). nrows % 16 == 0 -----------
__global__ __launch_bounds__(1024) void k_bnfinal(const float* __restrict__ part,
                                                  int nrows,
                                                  const float* __restrict__ g,
                                                  const float* __restrict__ be,
                                                  float invn,
                                                  float* __restrict__ a,
                                                  float* __restrict__ b) {
    __shared__ float sh[4][256];
    const int c = threadIdx.x & 255;
    const int q = threadIdx.x >> 8;
    const int per = nrows >> 2;
    float t = 0.f;
    for (int r = q * per; r < q * per + per; r += 4) {
        t += part[(r + 0) * 256 + c] + part[(r + 1) * 256 + c]
           + part[(r + 2) * 256 + c] + part[(r + 3) * 256 + c];
    }
    sh[q][c] = t;
    __syncthreads();
    if (threadIdx.x < 128) {
        int cc = threadIdx.x;
        float su = sh[0][cc] + sh[1][cc] + sh[2][cc] + sh[3][cc];
        float sq = sh[0][cc + 128] + sh[1][cc + 128]
                 + sh[2][cc + 128] + sh[3][cc + 128];
        float mu  = su * invn;
        float var = sq * invn - mu * mu;
        float av  = g[cc] * rsqrtf(var + 1e-5f);
        a[cc] = av;
        b[cc] = be[cc] - mu * av;
    }
}

// ---- CSR build ------------------------------------------------------------
__global__ __launch_bounds__(256) void k_count(const int* __restrict__ dst, int e,
                                               int* __restrict__ cnt) {
    int i = blockIdx.x * 256 + threadIdx.x;
    if (i < e) atomicAdd(&cnt[dst[i]], 1);
}

__global__ __launch_bounds__(1024) void k_scanA(const int* __restrict__ cnt, int n,
                                                int* __restrict__ rs, int* __restrict__ bsum) {
    __shared__ int tmp[1024];
    int t = threadIdx.x;
    int i = blockIdx.x * 1024 + t;
    int v = (i < n) ? cnt[i] : 0;
    tmp[t] = v;
    __syncthreads();
    for (int off = 1; off < 1024; off <<= 1) {
        int x = (t >= off) ? tmp[t - off] : 0;
        __syncthreads();
        tmp[t] += x;
        __syncthreads();
    }
    if (i < n) rs[i] = tmp[t] - v;
    if (t == 1023) bsum[blockIdx.x] = tmp[t];
}

__global__ __launch_bounds__(256) void k_scanC(int* __restrict__ rs,
                                               const int* __restrict__ bsum,
                                               const int* __restrict__ cnt,
                                               float* __restrict__ dinv,
                                               int n, int e) {
    __shared__ int base;
    int chunk = (int)(blockIdx.x >> 2);
    if (threadIdx.x == 0) {
        int s = 0;
        for (int c = 0; c < chunk; ++c) s += bsum[c];
        base = s;
    }
    __syncthreads();
    int i = blockIdx.x * 256 + threadIdx.x;
    if (i < n) {
        rs[i] += base;
        dinv[i] = rsqrtf((float)(cnt[i] + 1));
    }
    if (blockIdx.x == 0 && threadIdx.x == 0) rs[n] = e;
}

__global__ __launch_bounds__(256) void k_fill(const int* __restrict__ src,
                                              const int* __restrict__ dst, int e,
                                              const int* __restrict__ rs,
                                              int* __restrict__ cursor,
                                              const float* __restrict__ dinv,
                                              int2* __restrict__ ep) {
    int i = blockIdx.x * 256 + threadIdx.x;
    if (i < e) {
        int d = dst[i], s = src[i];
        int p = rs[d] + atomicAdd(&cursor[d], 1);
        float nm = dinv[s] * dinv[d];
        ep[p] = make_int2(s, __float_as_int(nm));
    }
}

// ---- W pre-swizzle to MFMA frag order -------------------------------------
__global__ __launch_bounds__(256) void k_prep_w(const float* __restrict__ W,
                                                ushort* __restrict__ Wswz) {
    int t  = blockIdx.x * 256 + threadIdx.x;   // 0..2047
    int l  = t & 63;
    int fi = t >> 6;
    int ks = fi & 3, ct = fi >> 2;
    int c  = ct * 16 + (l & 15);
    int k0 = ks * 32 + ((l >> 4) << 3);
    ushort o[8];
    #pragma unroll
    for (int j = 0; j < 8; ++j)
        o[j] = f2bf(W[(size_t)(k0 + j) * 128 + c]);
    ushort4* dst = (ushort4*)(Wswz + (size_t)t * 8);
    dst[0] = make_ushort4(o[0], o[1], o[2], o[3]);
    dst[1] = make_ushort4(o[4], o[5], o[6], o[7]);
}

// ---- MFMA GEMM: H_bf16[n][128] = bf16( f(X) @ W ) -------------------------
__global__ __launch_bounds__(256) void k_gemm_mfma(const float* __restrict__ X,
                                                   const ushort* __restrict__ Wswz,
                                                   const float* __restrict__ av,
                                                   const float* __restrict__ bv,
                                                   int relu,
                                                   ushort* __restrict__ H, int n) {
    __shared__ ushort xb[64 * 128];   // 16 KB, swizzled: byte ^= (row&7)<<4
    const int tid  = threadIdx.x;
    const int row0 = blockIdx.x * 64;

    for (int i = tid; i < 64 * 32; i += 256) {
        int r = i >> 5, c4 = i & 31;
        int gr = row0 + r;
        float4 v = make_float4(0.f, 0.f, 0.f, 0.f);
        if (gr < n) v = ((const float4*)X)[(size_t)gr * 32 + c4];
        float4 a4 = ((const float4*)av)[c4];
        float4 b4 = ((const float4*)bv)[c4];
        v.x = fmaf(v.x, a4.x, b4.x);
        v.y = fmaf(v.y, a4.y, b4.y);
        v.z = fmaf(v.z, a4.z, b4.z);
        v.w = fmaf(v.w, a4.w, b4.w);
        if (relu) {
            v.x = fmaxf(v.x, 0.f); v.y = fmaxf(v.y, 0.f);
            v.z = fmaxf(v.z, 0.f); v.w = fmaxf(v.w, 0.f);
        }
        ushort4 pk = make_ushort4(f2bf(v.x), f2bf(v.y), f2bf(v.z), f2bf(v.w));
        int off = (r * 256 + c4 * 8) ^ ((r & 7) << 4);
        *(ushort4*)((char*)xb + off) = pk;
    }
    __syncthreads();

    const int wv = tid >> 6;
    const int l  = tid & 63;
    const int arow = wv * 16 + (l & 15);

    s8v afr[4];
    #pragma unroll
    for (int ks = 0; ks < 4; ++ks) {
        int off = (arow * 256 + ks * 64 + ((l >> 4) << 4)) ^ ((arow & 7) << 4);
        afr[ks] = *(const s8v*)((const char*)xb + off);
    }

    const s8v* wf = (const s8v*)Wswz;
    f4v acc[8];
    #pragma unroll
    for (int ct = 0; ct < 8; ++ct) {
        f4v c = {0.f, 0.f, 0.f, 0.f};
        #pragma unroll
        for (int ks = 0; ks < 4; ++ks) {
            s8v bb = wf[(ct * 4 + ks) * 64 + l];
            c = __builtin_amdgcn_mfma_f32_16x16x32_bf16(afr[ks], bb, c, 0, 0, 0);
        }
        acc[ct] = c;
    }

    const int rbase = row0 + wv * 16 + ((l >> 4) << 2);
    const int cidx  = l & 15;
    #pragma unroll
    for (int r = 0; r < 4; ++r) {
        int gr = rbase + r;
        if (gr < n) {
            #pragma unroll
            for (int ct = 0; ct < 8; ++ct)
                H[(size_t)gr * 128 + ct * 16 + cidx] = f2bf(acc[ct][r]);
        }
    }
}

// ---- aggregation + fused BN stats -----------------------------------------
// Grid-stride: AGG_BLOCKS blocks x 4 waves, one node per wave per step.
// Lane owns cols {2*lane, 2*lane+1}; per-lane sum/sumsq accumulated in regs,
// LDS-reduced across the 4 waves into part[block][256].
__global__ __launch_bounds__(256) void k_aggregate(const ushort* __restrict__ H,
                                                   const int* __restrict__ rs,
                                                   const int2* __restrict__ ep,
                                                   const float* __restrict__ dinv,
                                                   float* __restrict__ AGG,
                                                   float* __restrict__ part, int n) {
    __shared__ float red[4][128];
    __shared__ float redq[4][128];
    const int wv   = threadIdx.x >> 6;
    const int lane = threadIdx.x & 63;
    float sx = 0.f, sy = 0.f, qx = 0.f, qy = 0.f;

    for (int node = blockIdx.x * 4 + wv; node < n; node += AGG_BLOCKS * 4) {
        float sn = dinv[node]; sn *= sn;
        float2 self = bf2f2(((const uint*)(H + (size_t)node * 128))[lane]);
        float2 acc;
        acc.x = self.x * sn; acc.y = self.y * sn;
        int i  = rs[node];
        int i1 = rs[node + 1];
        for (; i + 16 <= i1; i += 16) {
            int2 p[16];
            uint v[16];
            #pragma unroll
            for (int k = 0; k < 16; ++k) p[k] = ep[i + k];
            #pragma unroll
            for (int k = 0; k < 16; ++k)
                v[k] = ((const uint*)(H + (size_t)p[k].x * 128))[lane];
            #pragma unroll
            for (int k = 0; k < 16; ++k) {
                float w = __int_as_float(p[k].y);
                float2 f = bf2f2(v[k]);
                acc.x = fmaf(w, f.x, acc.x);
                acc.y = fmaf(w, f.y, acc.y);
            }
        }
        if (i + 8 <= i1) {
            int2 p[8];
            uint v[8];
            #pragma unroll
            for (int k = 0; k < 8; ++k) p[k] = ep[i + k];
            #pragma unroll
            for (int k = 0; k < 8; ++k)
                v[k] = ((const uint*)(H + (size_t)p[k].x * 128))[lane];
            #pragma unroll
            for (int k = 0; k < 8; ++k) {
                float w = __int_as_float(p[k].y);
                float2 f = bf2f2(v[k]);
                acc.x = fmaf(w, f.x, acc.x);
                acc.y = fmaf(w, f.y, acc.y);
            }
            i += 8;
        }
        if (i + 4 <= i1) {
            int2 p[4];
            uint v[4];
            #pragma unroll
            for (int k = 0; k < 4; ++k) p[k] = ep[i + k];
            #pragma unroll
            for (int k = 0; k < 4; ++k)
                v[k] = ((const uint*)(H + (size_t)p[k].x * 128))[lane];
            #pragma unroll
            for (int k = 0; k < 4; ++k) {
                float w = __int_as_float(p[k].y);
                float2 f = bf2f2(v[k]);
                acc.x = fmaf(w, f.x, acc.x);
                acc.y = fmaf(w, f.y, acc.y);
            }
            i += 4;
        }
        for (; i < i1; ++i) {
            int2 p = ep[i];
            float w = __int_as_float(p.y);
            float2 f = bf2f2(((const uint*)(H + (size_t)p.x * 128))[lane]);
            acc.x = fmaf(w, f.x, acc.x);
            acc.y = fmaf(w, f.y, acc.y);
        }
        ((float2*)(AGG + (size_t)node * 128))[lane] = acc;
        sx += acc.x; sy += acc.y;
        qx = fmaf(acc.x, acc.x, qx);
        qy = fmaf(acc.y, acc.y, qy);
    }

    red[wv][2 * lane]      = sx;
    red[wv][2 * lane + 1]  = sy;
    redq[wv][2 * lane]     = qx;
    redq[wv][2 * lane + 1] = qy;
    __syncthreads();
    const int t = threadIdx.x;
    if (t < 128)
        part[(size_t)blockIdx.x * 256 + t] =
            red[0][t] + red[1][t] + red[2][t] + red[3][t];
    else {
        int c = t - 128;
        part[(size_t)blockIdx.x * 256 + t] =
            redq[0][c] + redq[1][c] + redq[2][c] + redq[3][c];
    }
}

// ---- final projection: OUT = relu(a*X+b) @ Wf + bf  (128 -> 40) -----------
__global__ __launch_bounds__(256) void k_gemm_out(const float* __restrict__ X,
                                                  const float* __restrict__ Wf,
                                                  const float* __restrict__ bfv,
                                                  const float* __restrict__ a,
                                                  const float* __restrict__ b,
                                                  float* __restrict__ OUT, int n) {
    __shared__ float xl[32 * 132];
    __shared__ float wt[40 * 132];
    const int tid = threadIdx.x;

    for (int i = tid; i < 128 * 40; i += 256) {
        int c = i / 40;
        int j = i - c * 40;
        wt[j * 132 + c] = Wf[i];
    }
    const int row0 = blockIdx.x * 32;
    for (int i = tid; i < 32 * 32; i += 256) {
        int r = i >> 5, c4 = i & 31;
        int gr = row0 + r;
        float4 v = make_float4(0.f, 0.f, 0.f, 0.f);
        if (gr < n) v = ((const float4*)X)[(size_t)gr * 32 + c4];
        float4 a4 = ((const float4*)a)[c4];
        float4 b4 = ((const float4*)b)[c4];
        v.x = fmaxf(fmaf(v.x, a4.x, b4.x), 0.f);
        v.y = fmaxf(fmaf(v.y, a4.y, b4.y), 0.f);
        v.z = fmaxf(fmaf(v.z, a4.z, b4.z), 0.f);
        v.w = fmaxf(fmaf(v.w, a4.w, b4.w), 0.f);
        *(float4*)&xl[r * 132 + (c4 << 2)] = v;
    }
    __syncthreads();

    const int rg = tid >> 3;
    const int cg = tid & 7;
    const int j0 = cg * 5;
    float acc[5] = {0.f, 0.f, 0.f, 0.f, 0.f};
    for (int c = 0; c < 128; c += 4) {
        float4 xv = *(const float4*)&xl[rg * 132 + c];
        #pragma unroll
        for (int j = 0; j < 5; ++j) {
            float4 wv = *(const float4*)&wt[(j0 + j) * 132 + c];
            acc[j] = fmaf(xv.x, wv.x, acc[j]);
            acc[j] = fmaf(xv.y, wv.y, acc[j]);
            acc[j] = fmaf(xv.z, wv.z, acc[j]);
            acc[j] = fmaf(xv.w, wv.w, acc[j]);
        }
    }
    int gr = row0 + rg;
    if (gr < n) {
        #pragma unroll
        for (int j = 0; j < 5; ++j)
            OUT[(size_t)gr * 40 + j0 + j] = acc[j] + bfv[j0 + j];
    }
}

// ---------------------------------------------------------------------------
extern "C" void kernel_launch(void* const* d_in, const int* in_sizes, int n_in,
                              void* d_out, int out_size, void* d_ws, size_t ws_size,
                              hipStream_t stream) {
    const float* X0      = (const float*)d_in[0];
    const int*   edgesrc = (const int*)d_in[1];
    const int*   edgedst = (const int*)d_in[2];
    const float* bn0g = (const float*)d_in[3];
    const float* bn0b = (const float*)d_in[4];
    const float* W1   = (const float*)d_in[5];
    const float* bn1g = (const float*)d_in[7];
    const float* bn1b = (const float*)d_in[8];
    const float* W2   = (const float*)d_in[9];
    const float* bn2g = (const float*)d_in[11];
    const float* bn2b = (const float*)d_in[12];
    const float* Wf   = (const float*)d_in[13];
    const float* bfv  = (const float*)d_in[14];

    const int n = in_sizes[0] / 128;
    const int e = in_sizes[1];
    float* OUT = (float*)d_out;

    // workspace layout
    ushort* H    = (ushort*)d_ws;                     // n*128 bf16
    float*  AGG  = (float*)(H + (size_t)n * 128);     // n*128 f32
    float*  dinv = AGG + (size_t)n * 128;             // n
    int2*   ep   = (int2*)(dinv + n);                 // e
    ushort* Wswz = (ushort*)(ep + e);                 // 2 * 16384 bf16
    int*    cnt  = (int*)(Wswz + 2 * 16384);          // n
    int*    rs   = cnt + n;                           // n+1
    int*  cursor = rs + n + 1;                        // n
    int*    bsum = cursor + n;                        // 64
    float*  part = (float*)(bsum + 64);               // AGG_BLOCKS*256 (2 MB)
    float* part2 = part + (size_t)AGG_BLOCKS * 256;   // 64*256
    float* a0 = part2 + 64 * 256;       float* b0 = a0 + 128;
    float* a1 = b0 + 128;               float* b1 = a1 + 128;
    float* a2 = b1 + 128;               float* b2 = a2 + 128;

    hipMemsetAsync(cnt,    0, (size_t)n * sizeof(int), stream);
    hipMemsetAsync(cursor, 0, (size_t)n * sizeof(int), stream);

    const float invn = 1.f / (float)n;
    const int nb = (n + 1023) / 1024;

    k_prep_w<<<8, 256, 0, stream>>>(W1, Wswz);
    k_prep_w<<<8, 256, 0, stream>>>(W2, Wswz + 16384);

    // CSR build
    k_count<<<(e + 255) / 256, 256, 0, stream>>>(edgedst, e, cnt);
    k_scanA<<<nb, 1024, 0, stream>>>(cnt, n, rs, bsum);
    k_scanC<<<(n + 255) / 256, 256, 0, stream>>>(rs, bsum, cnt, dinv, n, e);
    k_fill<<<(e + 255) / 256, 256, 0, stream>>>(edgesrc, edgedst, e, rs, cursor,
                                                dinv, ep);

    const int gemmBlocks = (n + 63) / 64;

    // layer 1
    k_colstats<<<CS_BLOCKS, 256, 0, stream>>>(X0, n, part);
    k_bnfinal<<<1, 1024, 0, stream>>>(part, CS_BLOCKS, bn0g, bn0b, invn, a0, b0);
    k_gemm_mfma<<<gemmBlocks, 256, 0, stream>>>(X0, Wswz, a0, b0, 0, H, n);
    k_aggregate<<<AGG_BLOCKS, 256, 0, stream>>>(H, rs, ep, dinv, AGG, part, n);

    // layer 2 (stats of AGG came fused from aggregate)
    k_redA<<<64, 256, 0, stream>>>(part, part2);
    k_bnfinal<<<1, 1024, 0, stream>>>(part2, 64, bn1g, bn1b, invn, a1, b1);
    k_gemm_mfma<<<gemmBlocks, 256, 0, stream>>>(AGG, Wswz + 16384, a1, b1, 1, H, n);
    k_aggregate<<<AGG_BLOCKS, 256, 0, stream>>>(H, rs, ep, dinv, AGG, part, n);

    // head
    k_redA<<<64, 256, 0, stream>>>(part, part2);
    k_bnfinal<<<1, 1024, 0, stream>>>(part2, 64, bn2g, bn2b, invn, a2, b2);
    k_gemm_out<<<(n + 31) / 32, 256, 0, stream>>>(AGG, Wf, bfv, a2, b2, OUT, n);
}